// Round 1
// baseline (372.936 us; speedup 1.0000x reference)
//
#include <hip/hip_runtime.h>

// Problem constants (B=4, S=4096, D_MODEL=1024, H*Dk=H*Dv=1024)
#define M_TOT 16384
#define DM    1024
#define BM    128
#define BN    128
#define BK    32
#define KTILES (DM / BK)   // 32

typedef unsigned short ushort_t;
typedef __bf16 bf16x8 __attribute__((ext_vector_type(8)));
typedef float  f32x4  __attribute__((ext_vector_type(4)));

__device__ __forceinline__ ushort_t f32_to_bf16(float f) {
    union { float f; unsigned u; } v; v.f = f;
    unsigned u = v.u;
    return (ushort_t)((u + 0x7fffu + ((u >> 16) & 1u)) >> 16);   // RNE
}
__device__ __forceinline__ float bf16_to_f32(ushort_t h) {
    union { unsigned u; float f; } v; v.u = ((unsigned)h) << 16;
    return v.f;
}

typedef const __attribute__((address_space(1))) void* as1_cvoidp;
typedef __attribute__((address_space(3))) void*       as3_voidp;

// async global->LDS, 16B per lane; LDS dest = wave-uniform base + lane*16
__device__ __forceinline__ void gload_lds16(const ushort_t* g, ushort_t* s) {
    __builtin_amdgcn_global_load_lds((as1_cvoidp)g, (as3_voidp)s, 16, 0, 0);
}

// ---------------- fp32 -> bf16 conversion ----------------
__global__ __launch_bounds__(256) void cvt_f32_bf16(const float* __restrict__ src,
                                                    ushort_t* __restrict__ dst, int n4) {
    int i = blockIdx.x * 256 + threadIdx.x;
    if (i < n4) {
        const float4 v = ((const float4*)src)[i];
        ushort4 o;
        o.x = f32_to_bf16(v.x); o.y = f32_to_bf16(v.y);
        o.z = f32_to_bf16(v.z); o.w = f32_to_bf16(v.w);
        ((ushort4*)dst)[i] = o;
    }
}

// ---------------- GEMM1: V & g with shared A-tile, fused silu-gate ----------------
// A [16384,1024] bf16 row-major; Wv,Wg [1024,1024] bf16 row-major [out,in]
// gated[m,n] = (A@Wv^T)[m,n] * silu((A@Wg^T)[m,n]), written bf16
__global__ __launch_bounds__(256) void gemm_vg(
    const ushort_t* __restrict__ A,
    const ushort_t* __restrict__ Wv,
    const ushort_t* __restrict__ Wg,
    ushort_t* __restrict__ gated)
{
    __shared__ __align__(16) ushort_t As[BM * BK];
    __shared__ __align__(16) ushort_t Bv[BN * BK];
    __shared__ __align__(16) ushort_t Bg[BN * BK];

    const int tid  = threadIdx.x;
    const int wave = tid >> 6;
    const int lane = tid & 63;
    const int m0 = blockIdx.y * BM;
    const int n0 = blockIdx.x * BN;

    f32x4 accv[4][4], accg[4][4];
    const f32x4 vzero = {0.f, 0.f, 0.f, 0.f};
#pragma unroll
    for (int i = 0; i < 4; ++i)
#pragma unroll
        for (int j = 0; j < 4; ++j) { accv[i][j] = vzero; accg[i][j] = vzero; }

    // staging: tile = 512 chunks of 8 bf16 (16B); wave w covers chunks [w*128, w*128+128)
    const int c0 = wave * 128 + lane;
    const int r0 = c0 >> 2, x0c = (c0 & 3) << 3;
    const int c1 = c0 + 64;
    const int r1 = c1 >> 2, x1c = (c1 & 3) << 3;
    ushort_t* sA0 = As + wave * 1024;          // wave-uniform LDS bases
    ushort_t* sA1 = As + wave * 1024 + 512;
    ushort_t* sV0 = Bv + wave * 1024;
    ushort_t* sV1 = Bv + wave * 1024 + 512;
    ushort_t* sG0 = Bg + wave * 1024;
    ushort_t* sG1 = Bg + wave * 1024 + 512;

    const int fr   = lane & 15;
    const int quad = lane >> 4;
    const int ko   = quad << 3;
    const int wmBase = (wave >> 1) * 64;
    const int wnBase = (wave & 1) * 64;

    for (int kt = 0; kt < KTILES; ++kt) {
        const int k0 = kt * BK;
        __syncthreads();
        gload_lds16(A  + (m0 + r0) * DM + k0 + x0c, sA0);
        gload_lds16(A  + (m0 + r1) * DM + k0 + x1c, sA1);
        gload_lds16(Wv + (n0 + r0) * DM + k0 + x0c, sV0);
        gload_lds16(Wv + (n0 + r1) * DM + k0 + x1c, sV1);
        gload_lds16(Wg + (n0 + r0) * DM + k0 + x0c, sG0);
        gload_lds16(Wg + (n0 + r1) * DM + k0 + x1c, sG1);
        __syncthreads();

        bf16x8 af[4];
#pragma unroll
        for (int i = 0; i < 4; ++i)
            af[i] = *(const bf16x8*)(As + (wmBase + i * 16 + fr) * BK + ko);
#pragma unroll
        for (int j = 0; j < 4; ++j) {
            bf16x8 bv = *(const bf16x8*)(Bv + (wnBase + j * 16 + fr) * BK + ko);
            bf16x8 bg = *(const bf16x8*)(Bg + (wnBase + j * 16 + fr) * BK + ko);
#pragma unroll
            for (int i = 0; i < 4; ++i) {
                accv[i][j] = __builtin_amdgcn_mfma_f32_16x16x32_bf16(af[i], bv, accv[i][j], 0, 0, 0);
                accg[i][j] = __builtin_amdgcn_mfma_f32_16x16x32_bf16(af[i], bg, accg[i][j], 0, 0, 0);
            }
        }
    }

    // epilogue: gated = V * silu(g); C/D layout: col=lane&15, row=quad*4+reg
#pragma unroll
    for (int i = 0; i < 4; ++i) {
#pragma unroll
        for (int j = 0; j < 4; ++j) {
            const int colg = n0 + wnBase + j * 16 + fr;
#pragma unroll
            for (int r = 0; r < 4; ++r) {
                const int rowg = m0 + wmBase + i * 16 + quad * 4 + r;
                float v = accv[i][j][r];
                float g = accg[i][j][r];
                float gate = g / (1.0f + __expf(-g));   // silu
                gated[rowg * DM + colg] = f32_to_bf16(v * gate);
            }
        }
    }
}

// ---------------- GEMM2: proj = gated @ Wo^T, + residual x, store pre (bf16) ----------------
__global__ __launch_bounds__(256) void gemm_o(
    const ushort_t* __restrict__ A,    // gated bf16 [16384,1024]
    const ushort_t* __restrict__ Wo,   // [1024,1024] bf16 [out,in]
    const float*    __restrict__ X,    // residual fp32 [16384,1024]
    ushort_t* __restrict__ preout)     // pre = proj + x, bf16
{
    __shared__ __align__(16) ushort_t As[BM * BK];
    __shared__ __align__(16) ushort_t Bs[BN * BK];

    const int tid  = threadIdx.x;
    const int wave = tid >> 6;
    const int lane = tid & 63;
    const int m0 = blockIdx.y * BM;
    const int n0 = blockIdx.x * BN;

    f32x4 acc[4][4];
    const f32x4 vzero = {0.f, 0.f, 0.f, 0.f};
#pragma unroll
    for (int i = 0; i < 4; ++i)
#pragma unroll
        for (int j = 0; j < 4; ++j) acc[i][j] = vzero;

    const int c0 = wave * 128 + lane;
    const int r0 = c0 >> 2, x0c = (c0 & 3) << 3;
    const int c1 = c0 + 64;
    const int r1 = c1 >> 2, x1c = (c1 & 3) << 3;
    ushort_t* sA0 = As + wave * 1024;
    ushort_t* sA1 = As + wave * 1024 + 512;
    ushort_t* sB0 = Bs + wave * 1024;
    ushort_t* sB1 = Bs + wave * 1024 + 512;

    const int fr   = lane & 15;
    const int quad = lane >> 4;
    const int ko   = quad << 3;
    const int wmBase = (wave >> 1) * 64;
    const int wnBase = (wave & 1) * 64;

    for (int kt = 0; kt < KTILES; ++kt) {
        const int k0 = kt * BK;
        __syncthreads();
        gload_lds16(A  + (m0 + r0) * DM + k0 + x0c, sA0);
        gload_lds16(A  + (m0 + r1) * DM + k0 + x1c, sA1);
        gload_lds16(Wo + (n0 + r0) * DM + k0 + x0c, sB0);
        gload_lds16(Wo + (n0 + r1) * DM + k0 + x1c, sB1);
        __syncthreads();

        bf16x8 af[4];
#pragma unroll
        for (int i = 0; i < 4; ++i)
            af[i] = *(const bf16x8*)(As + (wmBase + i * 16 + fr) * BK + ko);
#pragma unroll
        for (int j = 0; j < 4; ++j) {
            bf16x8 bw = *(const bf16x8*)(Bs + (wnBase + j * 16 + fr) * BK + ko);
#pragma unroll
            for (int i = 0; i < 4; ++i)
                acc[i][j] = __builtin_amdgcn_mfma_f32_16x16x32_bf16(af[i], bw, acc[i][j], 0, 0, 0);
        }
    }

#pragma unroll
    for (int i = 0; i < 4; ++i) {
#pragma unroll
        for (int j = 0; j < 4; ++j) {
            const int colg = n0 + wnBase + j * 16 + fr;
#pragma unroll
            for (int r = 0; r < 4; ++r) {
                const int rowg = m0 + wmBase + i * 16 + quad * 4 + r;
                float pre = acc[i][j][r] + X[rowg * DM + colg];
                preout[rowg * DM + colg] = f32_to_bf16(pre);
            }
        }
    }
}

// ---------------- LayerNorm over rows of 1024 ----------------
__global__ __launch_bounds__(256) void ln_rows(const ushort_t* __restrict__ pre,
                                               const float* __restrict__ gamma,
                                               const float* __restrict__ beta,
                                               float* __restrict__ out)
{
    const int row = blockIdx.x;
    const int tid = threadIdx.x;
    const int wave = tid >> 6, lane = tid & 63;

    ushort4 u = ((const ushort4*)(pre + row * DM))[tid];
    float p0 = bf16_to_f32(u.x), p1 = bf16_to_f32(u.y);
    float p2 = bf16_to_f32(u.z), p3 = bf16_to_f32(u.w);

    float s  = p0 + p1 + p2 + p3;
    float ss = p0 * p0 + p1 * p1 + p2 * p2 + p3 * p3;
#pragma unroll
    for (int off = 32; off > 0; off >>= 1) {
        s  += __shfl_down(s, off);
        ss += __shfl_down(ss, off);
    }
    __shared__ float red[8];
    __shared__ float mb[2];
    if (lane == 0) { red[wave] = s; red[4 + wave] = ss; }
    __syncthreads();
    if (tid == 0) {
        float S  = red[0] + red[1] + red[2] + red[3];
        float SS = red[4] + red[5] + red[6] + red[7];
        float mean = S * (1.0f / 1024.0f);
        float var  = SS * (1.0f / 1024.0f) - mean * mean;
        mb[0] = mean;
        mb[1] = rsqrtf(var + 1e-5f);
    }
    __syncthreads();
    const float mean = mb[0], rs = mb[1];

    float4 gm = ((const float4*)gamma)[tid];
    float4 bt = ((const float4*)beta)[tid];
    float4 o;
    o.x = (p0 - mean) * rs * gm.x + bt.x;
    o.y = (p1 - mean) * rs * gm.y + bt.y;
    o.z = (p2 - mean) * rs * gm.z + bt.z;
    o.w = (p3 - mean) * rs * gm.w + bt.w;
    ((float4*)(out + row * DM))[tid] = o;
}

// ---------------- launch ----------------
extern "C" void kernel_launch(void* const* d_in, const int* in_sizes, int n_in,
                              void* d_out, int out_size, void* d_ws, size_t ws_size,
                              hipStream_t stream) {
    // setup_inputs order: x, W_Q, W_K, W_V, W_g, W_alpha, W_O, ln_gamma, ln_beta
    const float* x     = (const float*)d_in[0];
    const float* WV    = (const float*)d_in[3];
    const float* WG    = (const float*)d_in[4];
    const float* WO    = (const float*)d_in[6];
    const float* gamma = (const float*)d_in[7];
    const float* beta  = (const float*)d_in[8];
    float* out = (float*)d_out;

    // ws layout: [0,32MB): x_bf16 (later reused as pre) | [32,64MB): gated | [64MB..): weights bf16
    char* ws = (char*)d_ws;
    ushort_t* xb    = (ushort_t*)ws;
    ushort_t* gated = (ushort_t*)(ws + (size_t)M_TOT * DM * 2);
    ushort_t* wvb   = (ushort_t*)(ws + (size_t)M_TOT * DM * 4);
    ushort_t* wgb   = (ushort_t*)(ws + (size_t)M_TOT * DM * 4 + (size_t)DM * DM * 2);
    ushort_t* wob   = (ushort_t*)(ws + (size_t)M_TOT * DM * 4 + (size_t)DM * DM * 4);
    ushort_t* pre   = xb;  // alias: x_bf16 dead after gemm_vg

    cvt_f32_bf16<<<(M_TOT * DM / 4 + 255) / 256, 256, 0, stream>>>(x, xb, M_TOT * DM / 4);
    cvt_f32_bf16<<<(DM * DM / 4 + 255) / 256, 256, 0, stream>>>(WV, wvb, DM * DM / 4);
    cvt_f32_bf16<<<(DM * DM / 4 + 255) / 256, 256, 0, stream>>>(WG, wgb, DM * DM / 4);
    cvt_f32_bf16<<<(DM * DM / 4 + 255) / 256, 256, 0, stream>>>(WO, wob, DM * DM / 4);

    dim3 grid(DM / BN, M_TOT / BM);   // (8, 128)
    gemm_vg<<<grid, 256, 0, stream>>>(xb, wvb, wgb, gated);
    gemm_o <<<grid, 256, 0, stream>>>(gated, wob, x, pre);
    ln_rows<<<M_TOT, 256, 0, stream>>>(pre, gamma, beta, out);
}

// Round 2
// 293.522 us; speedup vs baseline: 1.2706x; 1.2706x over previous
//
#include <hip/hip_runtime.h>

// Problem constants (B=4, S=4096, D_MODEL=1024, H*Dk=H*Dv=1024)
#define M_TOT 16384
#define DM    1024
#define BK    32
#define KTILES (DM / BK)   // 32

typedef unsigned short ushort_t;
typedef __bf16 bf16x8 __attribute__((ext_vector_type(8)));
typedef float  f32x4  __attribute__((ext_vector_type(4)));

__device__ __forceinline__ ushort_t f32_to_bf16(float f) {
    union { float f; unsigned u; } v; v.f = f;
    unsigned u = v.u;
    return (ushort_t)((u + 0x7fffu + ((u >> 16) & 1u)) >> 16);   // RNE
}
__device__ __forceinline__ float bf16_to_f32(ushort_t h) {
    union { unsigned u; float f; } v; v.u = ((unsigned)h) << 16;
    return v.f;
}

typedef const __attribute__((address_space(1))) void* as1_cvoidp;
typedef __attribute__((address_space(3))) void*       as3_voidp;

// async global->LDS, 16B per lane; LDS dest = wave-uniform base + lane*16
__device__ __forceinline__ void gload_lds16(const ushort_t* g, ushort_t* s) {
    __builtin_amdgcn_global_load_lds((as1_cvoidp)g, (as3_voidp)s, 16, 0, 0);
}

// ---------------- fp32 -> bf16 conversion ----------------
__global__ __launch_bounds__(256) void cvt_f32_bf16(const float* __restrict__ src,
                                                    ushort_t* __restrict__ dst, int n4) {
    int i = blockIdx.x * 256 + threadIdx.x;
    if (i < n4) {
        const float4 v = ((const float4*)src)[i];
        ushort4 o;
        o.x = f32_to_bf16(v.x); o.y = f32_to_bf16(v.y);
        o.z = f32_to_bf16(v.z); o.w = f32_to_bf16(v.w);
        ((ushort4*)dst)[i] = o;
    }
}

// weights: 3 matrices of DM*DM, select by blockIdx.y
__global__ __launch_bounds__(256) void cvt_w3(const float* __restrict__ w0,
                                              const float* __restrict__ w1,
                                              const float* __restrict__ w2,
                                              ushort_t* __restrict__ d0,
                                              ushort_t* __restrict__ d1,
                                              ushort_t* __restrict__ d2) {
    const float* src = blockIdx.y == 0 ? w0 : (blockIdx.y == 1 ? w1 : w2);
    ushort_t*    dst = blockIdx.y == 0 ? d0 : (blockIdx.y == 1 ? d1 : d2);
    int i = blockIdx.x * 256 + threadIdx.x;   // grid.x covers DM*DM/4
    const float4 v = ((const float4*)src)[i];
    ushort4 o;
    o.x = f32_to_bf16(v.x); o.y = f32_to_bf16(v.y);
    o.z = f32_to_bf16(v.z); o.w = f32_to_bf16(v.w);
    ((ushort4*)dst)[i] = o;
}

// ---------------- GEMM1: V & g with shared A-tile, fused silu-gate ----------------
// Block tile 128x64, wave tile 64x32, dual accumulators (64 AGPR total).
// gated[m,n] = (A@Wv^T)[m,n] * silu((A@Wg^T)[m,n]), bf16 out.
__global__ __launch_bounds__(256) void gemm_vg(
    const ushort_t* __restrict__ A,
    const ushort_t* __restrict__ Wv,
    const ushort_t* __restrict__ Wg,
    ushort_t* __restrict__ gated)
{
    __shared__ __align__(16) ushort_t As[128 * BK];  // 8 KB
    __shared__ __align__(16) ushort_t Bv[64 * BK];   // 4 KB
    __shared__ __align__(16) ushort_t Bg[64 * BK];   // 4 KB

    const int tid  = threadIdx.x;
    const int wave = tid >> 6;
    const int lane = tid & 63;
    const int m0 = blockIdx.y * 128;
    const int n0 = blockIdx.x * 64;

    f32x4 accv[4][2], accg[4][2];
    const f32x4 vzero = {0.f, 0.f, 0.f, 0.f};
#pragma unroll
    for (int i = 0; i < 4; ++i)
#pragma unroll
        for (int j = 0; j < 2; ++j) { accv[i][j] = vzero; accg[i][j] = vzero; }

    // staging with XOR swizzle: LDS chunk c (row=c>>2, sc=c&3) holds global
    // chunk sc ^ ((row>>1)&3) = (c&3) ^ ((c>>3)&3)
    const int cA0 = wave * 128 + lane;
    const int rA0 = cA0 >> 2, gA0 = (((cA0 & 3) ^ ((cA0 >> 3) & 3)) << 3);
    const int cA1 = cA0 + 64;
    const int rA1 = cA1 >> 2, gA1 = (((cA1 & 3) ^ ((cA1 >> 3) & 3)) << 3);
    const int cB  = wave * 64 + lane;
    const int rB  = cB >> 2,  gB  = (((cB & 3) ^ ((cB >> 3) & 3)) << 3);

    ushort_t* sA0 = As + wave * 1024;          // wave-uniform LDS bases
    ushort_t* sA1 = As + wave * 1024 + 512;
    ushort_t* sBv = Bv + wave * 512;
    ushort_t* sBg = Bg + wave * 512;

    const int fr   = lane & 15;
    const int quad = lane >> 4;
    const int sw   = ((quad ^ ((fr >> 1) & 3)) << 3);   // swizzled k-chunk offset
    const int wmBase = (wave >> 1) * 64;
    const int wnBase = (wave & 1) * 32;

    for (int kt = 0; kt < KTILES; ++kt) {
        const int k0 = kt * BK;
        __syncthreads();
        gload_lds16(A  + (m0 + rA0) * DM + k0 + gA0, sA0);
        gload_lds16(A  + (m0 + rA1) * DM + k0 + gA1, sA1);
        gload_lds16(Wv + (n0 + rB)  * DM + k0 + gB,  sBv);
        gload_lds16(Wg + (n0 + rB)  * DM + k0 + gB,  sBg);
        __syncthreads();

        bf16x8 af[4];
#pragma unroll
        for (int i = 0; i < 4; ++i)
            af[i] = *(const bf16x8*)(As + (wmBase + i * 16 + fr) * BK + sw);
#pragma unroll
        for (int j = 0; j < 2; ++j) {
            bf16x8 bv = *(const bf16x8*)(Bv + (wnBase + j * 16 + fr) * BK + sw);
            bf16x8 bg = *(const bf16x8*)(Bg + (wnBase + j * 16 + fr) * BK + sw);
#pragma unroll
            for (int i = 0; i < 4; ++i) {
                accv[i][j] = __builtin_amdgcn_mfma_f32_16x16x32_bf16(af[i], bv, accv[i][j], 0, 0, 0);
                accg[i][j] = __builtin_amdgcn_mfma_f32_16x16x32_bf16(af[i], bg, accg[i][j], 0, 0, 0);
            }
        }
    }

    // epilogue: gated = V * silu(g); C/D layout: col=lane&15, row=quad*4+reg
#pragma unroll
    for (int i = 0; i < 4; ++i) {
#pragma unroll
        for (int j = 0; j < 2; ++j) {
            const int colg = n0 + wnBase + j * 16 + fr;
#pragma unroll
            for (int r = 0; r < 4; ++r) {
                const int rowg = m0 + wmBase + i * 16 + quad * 4 + r;
                float v = accv[i][j][r];
                float g = accg[i][j][r];
                float gate = g / (1.0f + __expf(-g));   // silu
                gated[rowg * DM + colg] = f32_to_bf16(v * gate);
            }
        }
    }
}

// ---------------- GEMM2: proj = gated @ Wo^T, + residual x, store pre (bf16) ----------------
// Block tile 128x128 (m97 sweet spot), single acc, swizzled LDS.
__global__ __launch_bounds__(256) void gemm_o(
    const ushort_t* __restrict__ A,    // gated bf16 [16384,1024]
    const ushort_t* __restrict__ Wo,   // [1024,1024] bf16 [out,in]
    const float*    __restrict__ X,    // residual fp32 [16384,1024]
    ushort_t* __restrict__ preout)     // pre = proj + x, bf16
{
    __shared__ __align__(16) ushort_t As[128 * BK];
    __shared__ __align__(16) ushort_t Bs[128 * BK];

    const int tid  = threadIdx.x;
    const int wave = tid >> 6;
    const int lane = tid & 63;
    const int m0 = blockIdx.y * 128;
    const int n0 = blockIdx.x * 128;

    f32x4 acc[4][4];
    const f32x4 vzero = {0.f, 0.f, 0.f, 0.f};
#pragma unroll
    for (int i = 0; i < 4; ++i)
#pragma unroll
        for (int j = 0; j < 4; ++j) acc[i][j] = vzero;

    const int c0 = wave * 128 + lane;
    const int r0 = c0 >> 2, g0 = (((c0 & 3) ^ ((c0 >> 3) & 3)) << 3);
    const int c1 = c0 + 64;
    const int r1 = c1 >> 2, g1 = (((c1 & 3) ^ ((c1 >> 3) & 3)) << 3);
    ushort_t* sA0 = As + wave * 1024;
    ushort_t* sA1 = As + wave * 1024 + 512;
    ushort_t* sB0 = Bs + wave * 1024;
    ushort_t* sB1 = Bs + wave * 1024 + 512;

    const int fr   = lane & 15;
    const int quad = lane >> 4;
    const int sw   = ((quad ^ ((fr >> 1) & 3)) << 3);
    const int wmBase = (wave >> 1) * 64;
    const int wnBase = (wave & 1) * 64;

    for (int kt = 0; kt < KTILES; ++kt) {
        const int k0 = kt * BK;
        __syncthreads();
        gload_lds16(A  + (m0 + r0) * DM + k0 + g0, sA0);
        gload_lds16(A  + (m0 + r1) * DM + k0 + g1, sA1);
        gload_lds16(Wo + (n0 + r0) * DM + k0 + g0, sB0);
        gload_lds16(Wo + (n0 + r1) * DM + k0 + g1, sB1);
        __syncthreads();

        bf16x8 af[4];
#pragma unroll
        for (int i = 0; i < 4; ++i)
            af[i] = *(const bf16x8*)(As + (wmBase + i * 16 + fr) * BK + sw);
#pragma unroll
        for (int j = 0; j < 4; ++j) {
            bf16x8 bw = *(const bf16x8*)(Bs + (wnBase + j * 16 + fr) * BK + sw);
#pragma unroll
            for (int i = 0; i < 4; ++i)
                acc[i][j] = __builtin_amdgcn_mfma_f32_16x16x32_bf16(af[i], bw, acc[i][j], 0, 0, 0);
        }
    }

#pragma unroll
    for (int i = 0; i < 4; ++i) {
#pragma unroll
        for (int j = 0; j < 4; ++j) {
            const int colg = n0 + wnBase + j * 16 + fr;
#pragma unroll
            for (int r = 0; r < 4; ++r) {
                const int rowg = m0 + wmBase + i * 16 + quad * 4 + r;
                float pre = acc[i][j][r] + X[rowg * DM + colg];
                preout[rowg * DM + colg] = f32_to_bf16(pre);
            }
        }
    }
}

// ---------------- LayerNorm over rows of 1024 ----------------
__global__ __launch_bounds__(256) void ln_rows(const ushort_t* __restrict__ pre,
                                               const float* __restrict__ gamma,
                                               const float* __restrict__ beta,
                                               float* __restrict__ out)
{
    const int row = blockIdx.x;
    const int tid = threadIdx.x;
    const int wave = tid >> 6, lane = tid & 63;

    ushort4 u = ((const ushort4*)(pre + row * DM))[tid];
    float p0 = bf16_to_f32(u.x), p1 = bf16_to_f32(u.y);
    float p2 = bf16_to_f32(u.z), p3 = bf16_to_f32(u.w);

    float s  = p0 + p1 + p2 + p3;
    float ss = p0 * p0 + p1 * p1 + p2 * p2 + p3 * p3;
#pragma unroll
    for (int off = 32; off > 0; off >>= 1) {
        s  += __shfl_down(s, off);
        ss += __shfl_down(ss, off);
    }
    __shared__ float red[8];
    __shared__ float mb[2];
    if (lane == 0) { red[wave] = s; red[4 + wave] = ss; }
    __syncthreads();
    if (tid == 0) {
        float S  = red[0] + red[1] + red[2] + red[3];
        float SS = red[4] + red[5] + red[6] + red[7];
        float mean = S * (1.0f / 1024.0f);
        float var  = SS * (1.0f / 1024.0f) - mean * mean;
        mb[0] = mean;
        mb[1] = rsqrtf(var + 1e-5f);
    }
    __syncthreads();
    const float mean = mb[0], rs = mb[1];

    float4 gm = ((const float4*)gamma)[tid];
    float4 bt = ((const float4*)beta)[tid];
    float4 o;
    o.x = (p0 - mean) * rs * gm.x + bt.x;
    o.y = (p1 - mean) * rs * gm.y + bt.y;
    o.z = (p2 - mean) * rs * gm.z + bt.z;
    o.w = (p3 - mean) * rs * gm.w + bt.w;
    ((float4*)(out + row * DM))[tid] = o;
}

// ---------------- launch ----------------
extern "C" void kernel_launch(void* const* d_in, const int* in_sizes, int n_in,
                              void* d_out, int out_size, void* d_ws, size_t ws_size,
                              hipStream_t stream) {
    // setup_inputs order: x, W_Q, W_K, W_V, W_g, W_alpha, W_O, ln_gamma, ln_beta
    const float* x     = (const float*)d_in[0];
    const float* WV    = (const float*)d_in[3];
    const float* WG    = (const float*)d_in[4];
    const float* WO    = (const float*)d_in[6];
    const float* gamma = (const float*)d_in[7];
    const float* beta  = (const float*)d_in[8];
    float* out = (float*)d_out;

    // ws layout: [0,32MB): x_bf16 (later reused as pre) | [32,64MB): gated | [64MB..): weights bf16
    char* ws = (char*)d_ws;
    ushort_t* xb    = (ushort_t*)ws;
    ushort_t* gated = (ushort_t*)(ws + (size_t)M_TOT * DM * 2);
    ushort_t* wvb   = (ushort_t*)(ws + (size_t)M_TOT * DM * 4);
    ushort_t* wgb   = (ushort_t*)(ws + (size_t)M_TOT * DM * 4 + (size_t)DM * DM * 2);
    ushort_t* wob   = (ushort_t*)(ws + (size_t)M_TOT * DM * 4 + (size_t)DM * DM * 4);
    ushort_t* pre   = xb;  // alias: x_bf16 dead after gemm_vg

    cvt_f32_bf16<<<(M_TOT * DM / 4 + 255) / 256, 256, 0, stream>>>(x, xb, M_TOT * DM / 4);
    cvt_w3<<<dim3(DM * DM / 4 / 256, 3), 256, 0, stream>>>(WV, WG, WO, wvb, wgb, wob);

    gemm_vg<<<dim3(DM / 64, M_TOT / 128), 256, 0, stream>>>(xb, wvb, wgb, gated);
    gemm_o <<<dim3(DM / 128, M_TOT / 128), 256, 0, stream>>>(gated, wob, x, pre);
    ln_rows<<<M_TOT, 256, 0, stream>>>(pre, gamma, beta, out);
}